// Round 6
// baseline (1138.757 us; speedup 1.0000x reference)
//
#include <hip/hip_runtime.h>
#include <stdint.h>

#define N_NODES 100000
#define N_EDGES 400000
#define N_GRAPHS 2000
#define C_IN 48
#define HD 128
#define NLAYERS 6
#define BN_EPS 1e-5f
#define NSLOPE 0.01f
#define SB 391   // ceil(N_NODES/256)
#define NREP 8   // stats replication factor (contention / NREP)

typedef uint16_t u16;
typedef uint32_t u32;
typedef short bf16x8 __attribute__((ext_vector_type(8)));
typedef float f32x4 __attribute__((ext_vector_type(4)));

__device__ __forceinline__ float bf2f_lo(u32 v) { return __uint_as_float(v << 16); }
__device__ __forceinline__ float bf2f_hi(u32 v) { return __uint_as_float(v & 0xffff0000u); }
__device__ __forceinline__ float bf2f(u16 h) { return __uint_as_float(((u32)h) << 16); }
__device__ __forceinline__ u16 f2bf(float f) {
    u32 u = __float_as_uint(f);
    u32 r = (u + 0x7fffu + ((u >> 16) & 1u)) >> 16;
    return (u16)r;
}
__device__ __forceinline__ u32 pack2(float a, float b) {
    return (u32)f2bf(a) | ((u32)f2bf(b) << 16);
}
__device__ __forceinline__ float lrelu(float v) { return v >= 0.f ? v : v * NSLOPE; }

// dtype detection: mode=1 -> float inputs are fp32; mode=0 -> bf16.
__global__ __launch_bounds__(256) void detect_kernel(const u16* __restrict__ x, int* __restrict__ mode) {
    __shared__ int flag;
    if (threadIdx.x == 0) flag = 0;
    __syncthreads();
    int local = 0;
    for (int i = threadIdx.x; i < 16384; i += 256) {
        float a = fabsf(bf2f(x[i]));
        if (!(a < 1e4f)) local = 1;
    }
    if (local) flag = 1;
    __syncthreads();
    if (threadIdx.x == 0) mode[0] = flag;
}

// ---------------- CSR build ----------------
__global__ __launch_bounds__(256) void hist_kernel(const int* __restrict__ dst, int* __restrict__ cnt) {
    int e = blockIdx.x * 256 + threadIdx.x;
    if (e < N_EDGES) atomicAdd(&cnt[dst[e]], 1);
}

__global__ __launch_bounds__(256) void scan1_kernel(const int* __restrict__ cnt, int* __restrict__ bsum) {
    __shared__ int s[256];
    const int t = threadIdx.x;
    const int i = blockIdx.x * 256 + t;
    s[t] = (i < N_NODES) ? cnt[i] : 0;
    __syncthreads();
    for (int d = 128; d > 0; d >>= 1) {
        if (t < d) s[t] += s[t + d];
        __syncthreads();
    }
    if (t == 0) bsum[blockIdx.x] = s[0];
}

__global__ __launch_bounds__(512) void scan2_kernel(int* __restrict__ bsum, int* __restrict__ row_ptr) {
    __shared__ int s[SB];
    const int t = threadIdx.x;
    if (t < SB) s[t] = bsum[t];
    __syncthreads();
    if (t == 0) {
        int run = 0;
        for (int b = 0; b < SB; ++b) { int v = s[b]; s[b] = run; run += v; }
        row_ptr[0] = 0;
    }
    __syncthreads();
    if (t < SB) bsum[t] = s[t];
}

__global__ __launch_bounds__(256) void scan3_kernel(const int* __restrict__ cnt, const int* __restrict__ bsum,
                                                    int* __restrict__ row_ptr) {
    __shared__ int s[256];
    const int t = threadIdx.x;
    const int i = blockIdx.x * 256 + t;
    s[t] = (i < N_NODES) ? cnt[i] : 0;
    __syncthreads();
    if (t == 0) {
        int run = bsum[blockIdx.x];
        for (int j = 0; j < 256; ++j) { run += s[j]; s[j] = run; }
    }
    __syncthreads();
    if (i < N_NODES) row_ptr[i + 1] = s[t];
}

__global__ __launch_bounds__(256) void fill_kernel(const int* __restrict__ src, const int* __restrict__ dst,
                                                   int* __restrict__ cursor, int* __restrict__ col_idx) {
    int e = blockIdx.x * 256 + threadIdx.x;
    if (e < N_EDGES) {
        int d = dst[e];
        int slot = atomicAdd(&cursor[d], 1);
        col_idx[slot] = src[e];
    }
}

// ---------------- weight pre-pack into MFMA B-fragment layout (bf16) ----------------
__global__ __launch_bounds__(256) void pack_w_kernel(const void* __restrict__ W1a, const void* __restrict__ W1b,
                                                     const void* __restrict__ W2, const int* __restrict__ mode,
                                                     u16* __restrict__ wpack) {
    const int t = blockIdx.x * 256 + threadIdx.x;  // 12*2048 = 24576
    if (t >= 24576) return;
    const int mat = t >> 11;
    const int r = t & 2047;
    const int l = r & 63;
    const int f = r >> 6;
    const int kb = f >> 3, nt = f & 7;
    const int k0 = kb * 32 + (l >> 4) * 8;
    const int n = nt * 16 + (l & 15);
    const int md = *mode;
    u16 vals[8];
    #pragma unroll
    for (int j = 0; j < 8; ++j) {
        const int k = k0 + j;
        float v;
        if (mat == 0) {
            v = (k < C_IN) ? (md ? ((const float*)W1a)[k * HD + n] : bf2f(((const u16*)W1a)[k * HD + n])) : 0.f;
        } else if (mat < 6) {
            const size_t o = (size_t)(mat - 1) * HD * HD + (size_t)k * HD + n;
            v = md ? ((const float*)W1b)[o] : bf2f(((const u16*)W1b)[o]);
        } else {
            const size_t o = (size_t)(mat - 6) * HD * HD + (size_t)k * HD + n;
            v = md ? ((const float*)W2)[o] : bf2f(((const u16*)W2)[o]);
        }
        vals[j] = f2bf(v);
    }
    uint4 o;
    o.x = (u32)vals[0] | ((u32)vals[1] << 16);
    o.y = (u32)vals[2] | ((u32)vals[3] << 16);
    o.z = (u32)vals[4] | ((u32)vals[5] << 16);
    o.w = (u32)vals[6] | ((u32)vals[7] << 16);
    *reinterpret_cast<uint4*>(wpack + (size_t)t * 8) = o;
}

// ---------------- aggregation: 4 nodes per wave, 8 gathers in flight ----------------
__global__ __launch_bounds__(256) void agg0_kernel(const void* __restrict__ xv, const int* __restrict__ row_ptr,
                                                   const int* __restrict__ col_idx, const int* __restrict__ mode,
                                                   u16* __restrict__ z) {
    const int wave = threadIdx.x >> 6, lane = threadIdx.x & 63;
    const int base = (blockIdx.x * 4 + wave) * 4;
    if (base >= N_NODES) return;
    const int md = *mode;
    int sq[4], dg[4], idxv[4];
    #pragma unroll
    for (int q = 0; q < 4; ++q) {
        const int nq = base + q;
        if (nq < N_NODES) { sq[q] = row_ptr[nq]; dg[q] = row_ptr[nq + 1] - sq[q]; }
        else { sq[q] = 0; dg[q] = 0; }
    }
    #pragma unroll
    for (int q = 0; q < 4; ++q)
        idxv[q] = (lane < min(dg[q], 64)) ? col_idx[sq[q] + lane] : 0;

    float a[4][2];
    const int bmax = max(max(min(dg[0], 64), min(dg[1], 64)), max(min(dg[2], 64), min(dg[3], 64)));

    if (md) {
        const float* xf = (const float*)xv;
        #pragma unroll
        for (int q = 0; q < 4; ++q) {
            a[q][0] = 0.f; a[q][1] = 0.f;
            if (base + q < N_NODES && lane < 24) {
                float2 v = *reinterpret_cast<const float2*>(xf + (size_t)(base + q) * C_IN + 2 * lane);
                a[q][0] = v.x; a[q][1] = v.y;
            }
        }
        for (int b = 0; b < bmax; b += 2) {
            float2 w[8];
            bool h[8];
            #pragma unroll
            for (int q = 0; q < 4; ++q) {
                const int dq = min(dg[q], 64);
                h[2 * q] = b < dq; h[2 * q + 1] = (b + 1) < dq;
                w[2 * q] = make_float2(0.f, 0.f); w[2 * q + 1] = make_float2(0.f, 0.f);
                if (h[2 * q] && lane < 24)
                    w[2 * q] = *reinterpret_cast<const float2*>(xf + (size_t)__shfl(idxv[q], b) * C_IN + 2 * lane);
                if (h[2 * q + 1] && lane < 24)
                    w[2 * q + 1] = *reinterpret_cast<const float2*>(xf + (size_t)__shfl(idxv[q], b + 1) * C_IN + 2 * lane);
            }
            #pragma unroll
            for (int q = 0; q < 4; ++q) {
                if (h[2 * q])     { a[q][0] += w[2 * q].x;     a[q][1] += w[2 * q].y; }
                if (h[2 * q + 1]) { a[q][0] += w[2 * q + 1].x; a[q][1] += w[2 * q + 1].y; }
            }
        }
        #pragma unroll
        for (int q = 0; q < 4; ++q) {  // rare deg>64 tail
            int done = 64;
            while (done < dg[q]) {
                const int n = min(dg[q] - done, 64);
                const int id = (lane < n) ? col_idx[sq[q] + done + lane] : 0;
                for (int b = 0; b < n; ++b) {
                    const int i = __shfl(id, b);
                    if (lane < 24) {
                        float2 wv = *reinterpret_cast<const float2*>(xf + (size_t)i * C_IN + 2 * lane);
                        a[q][0] += wv.x; a[q][1] += wv.y;
                    }
                }
                done += n;
            }
        }
    } else {
        const u16* xh = (const u16*)xv;
        #pragma unroll
        for (int q = 0; q < 4; ++q) {
            a[q][0] = 0.f; a[q][1] = 0.f;
            if (base + q < N_NODES && lane < 24) {
                u32 v = *reinterpret_cast<const u32*>(xh + (size_t)(base + q) * C_IN + 2 * lane);
                a[q][0] = bf2f_lo(v); a[q][1] = bf2f_hi(v);
            }
        }
        for (int b = 0; b < bmax; b += 2) {
            u32 w[8];
            bool h[8];
            #pragma unroll
            for (int q = 0; q < 4; ++q) {
                const int dq = min(dg[q], 64);
                h[2 * q] = b < dq; h[2 * q + 1] = (b + 1) < dq;
                w[2 * q] = 0; w[2 * q + 1] = 0;
                if (h[2 * q] && lane < 24)
                    w[2 * q] = *reinterpret_cast<const u32*>(xh + (size_t)__shfl(idxv[q], b) * C_IN + 2 * lane);
                if (h[2 * q + 1] && lane < 24)
                    w[2 * q + 1] = *reinterpret_cast<const u32*>(xh + (size_t)__shfl(idxv[q], b + 1) * C_IN + 2 * lane);
            }
            #pragma unroll
            for (int q = 0; q < 4; ++q) {
                if (h[2 * q])     { a[q][0] += bf2f_lo(w[2 * q]);     a[q][1] += bf2f_hi(w[2 * q]); }
                if (h[2 * q + 1]) { a[q][0] += bf2f_lo(w[2 * q + 1]); a[q][1] += bf2f_hi(w[2 * q + 1]); }
            }
        }
        #pragma unroll
        for (int q = 0; q < 4; ++q) {
            int done = 64;
            while (done < dg[q]) {
                const int n = min(dg[q] - done, 64);
                const int id = (lane < n) ? col_idx[sq[q] + done + lane] : 0;
                for (int b = 0; b < n; ++b) {
                    const int i = __shfl(id, b);
                    if (lane < 24) {
                        u32 wv = *reinterpret_cast<const u32*>(xh + (size_t)i * C_IN + 2 * lane);
                        a[q][0] += bf2f_lo(wv); a[q][1] += bf2f_hi(wv);
                    }
                }
                done += n;
            }
        }
    }
    #pragma unroll
    for (int q = 0; q < 4; ++q) {
        if (base + q < N_NODES) {
            const u32 outw = (lane < 24) ? pack2(a[q][0], a[q][1]) : 0u;
            *reinterpret_cast<u32*>(z + (size_t)(base + q) * HD + 2 * lane) = outw;
        }
    }
}

// Fused outer-BN+lrelu + gather; BN coefs from NREP-replicated raw stats.
__global__ __launch_bounds__(256) void agg_bn_kernel(const u16* __restrict__ u, const int* __restrict__ row_ptr,
                                                     const int* __restrict__ col_idx,
                                                     const float* __restrict__ stats,
                                                     const void* __restrict__ gammav, const void* __restrict__ betav,
                                                     size_t gelem, const int* __restrict__ mode,
                                                     u16* __restrict__ z) {
    const int wave = threadIdx.x >> 6, lane = threadIdx.x & 63;
    const int base = (blockIdx.x * 4 + wave) * 4;
    if (base >= N_NODES) return;
    const int md = *mode;
    const int j0 = 2 * lane;
    float sm0 = 0, sm1 = 0, sq_0 = 0, sq_1 = 0;
    #pragma unroll
    for (int rep = 0; rep < NREP; ++rep) {
        sm0 += stats[rep * 256 + j0];       sm1 += stats[rep * 256 + j0 + 1];
        sq_0 += stats[rep * 256 + 128 + j0]; sq_1 += stats[rep * 256 + 128 + j0 + 1];
    }
    const float inv_n = 1.0f / (float)N_NODES;
    const float mean0 = sm0 * inv_n, mean1 = sm1 * inv_n;
    const float var0 = fmaxf(sq_0 * inv_n - mean0 * mean0, 0.f);
    const float var1 = fmaxf(sq_1 * inv_n - mean1 * mean1, 0.f);
    const float g0 = md ? ((const float*)gammav)[gelem + j0] : bf2f(((const u16*)gammav)[gelem + j0]);
    const float g1v = md ? ((const float*)gammav)[gelem + j0 + 1] : bf2f(((const u16*)gammav)[gelem + j0 + 1]);
    const float be0 = md ? ((const float*)betav)[gelem + j0] : bf2f(((const u16*)betav)[gelem + j0]);
    const float be1 = md ? ((const float*)betav)[gelem + j0 + 1] : bf2f(((const u16*)betav)[gelem + j0 + 1]);
    const float A0 = g0 * rsqrtf(var0 + BN_EPS), B0 = be0 - A0 * mean0;
    const float A1 = g1v * rsqrtf(var1 + BN_EPS), B1 = be1 - A1 * mean1;

    int sq[4], dg[4], idxv[4];
    #pragma unroll
    for (int q = 0; q < 4; ++q) {
        const int nq = base + q;
        if (nq < N_NODES) { sq[q] = row_ptr[nq]; dg[q] = row_ptr[nq + 1] - sq[q]; }
        else { sq[q] = 0; dg[q] = 0; }
    }
    #pragma unroll
    for (int q = 0; q < 4; ++q)
        idxv[q] = (lane < min(dg[q], 64)) ? col_idx[sq[q] + lane] : 0;

    float a[4][2];
    #pragma unroll
    for (int q = 0; q < 4; ++q) {
        a[q][0] = 0.f; a[q][1] = 0.f;
        if (base + q < N_NODES) {
            u32 v = *reinterpret_cast<const u32*>(u + (size_t)(base + q) * HD + j0);
            a[q][0] = lrelu(A0 * bf2f_lo(v) + B0);
            a[q][1] = lrelu(A1 * bf2f_hi(v) + B1);
        }
    }
    const int bmax = max(max(min(dg[0], 64), min(dg[1], 64)), max(min(dg[2], 64), min(dg[3], 64)));
    for (int b = 0; b < bmax; b += 2) {
        u32 w[8];
        bool h[8];
        #pragma unroll
        for (int q = 0; q < 4; ++q) {
            const int dq = min(dg[q], 64);
            h[2 * q] = b < dq; h[2 * q + 1] = (b + 1) < dq;
            w[2 * q] = 0; w[2 * q + 1] = 0;
            if (h[2 * q])
                w[2 * q] = *reinterpret_cast<const u32*>(u + (size_t)__shfl(idxv[q], b) * HD + j0);
            if (h[2 * q + 1])
                w[2 * q + 1] = *reinterpret_cast<const u32*>(u + (size_t)__shfl(idxv[q], b + 1) * HD + j0);
        }
        #pragma unroll
        for (int q = 0; q < 4; ++q) {
            if (h[2 * q]) {
                a[q][0] += lrelu(A0 * bf2f_lo(w[2 * q]) + B0);
                a[q][1] += lrelu(A1 * bf2f_hi(w[2 * q]) + B1);
            }
            if (h[2 * q + 1]) {
                a[q][0] += lrelu(A0 * bf2f_lo(w[2 * q + 1]) + B0);
                a[q][1] += lrelu(A1 * bf2f_hi(w[2 * q + 1]) + B1);
            }
        }
    }
    #pragma unroll
    for (int q = 0; q < 4; ++q) {  // rare deg>64 tail
        int done = 64;
        while (done < dg[q]) {
            const int n = min(dg[q] - done, 64);
            const int id = (lane < n) ? col_idx[sq[q] + done + lane] : 0;
            for (int b = 0; b < n; ++b) {
                const int i = __shfl(id, b);
                const u32 wv = *reinterpret_cast<const u32*>(u + (size_t)i * HD + j0);
                a[q][0] += lrelu(A0 * bf2f_lo(wv) + B0);
                a[q][1] += lrelu(A1 * bf2f_hi(wv) + B1);
            }
            done += n;
        }
    }
    #pragma unroll
    for (int q = 0; q < 4; ++q)
        if (base + q < N_NODES)
            *reinterpret_cast<u32*>(z + (size_t)(base + q) * HD + j0) = pack2(a[q][0], a[q][1]);
}

// ---------------- MFMA GEMM with LDS-staged A and LDS-transposed epilogue ----------------
// STATS accumulates column sum/sumsq into NREP-replicated stats[rep][256] (rep = blockIdx&7).
// TRANS applies inner-BN+lrelu (coefs from replicated instats) while staging A.
// IN-PLACE SAFE (out == A): global A-reads only in staging; global writes only in final pass.
template <int TRANS, int STATS>
__global__ __launch_bounds__(256) void gemm_mfma(const u16* A, const u16* __restrict__ wp,
                                                 const void* __restrict__ biasv, size_t belem,
                                                 const float* __restrict__ instats,
                                                 const void* __restrict__ gammav, const void* __restrict__ betav,
                                                 size_t gelem, const int* __restrict__ mode,
                                                 u16* out, float* __restrict__ stats) {
    __shared__ u16 Asm[128][136];
    __shared__ float sred[4][128];
    __shared__ float sqred[4][128];
    const int md = *mode;
    const int tid = threadIdx.x;
    const int m0 = blockIdx.x * 128;
    const int rbase = tid >> 4;   // 0..15
    const int seg = tid & 15;     // cols seg*8 .. seg*8+7

    // ---- stage A tile (+ optional BN+lrelu) into LDS ----
    {
        float cA[8], cB[8];
        if (TRANS) {
            const float inv_n = 1.0f / (float)N_NODES;
            #pragma unroll
            for (int j = 0; j < 8; ++j) {
                const int c = seg * 8 + j;
                float sm = 0.f, sq = 0.f;
                #pragma unroll
                for (int rep = 0; rep < NREP; ++rep) {
                    sm += instats[rep * 256 + c];
                    sq += instats[rep * 256 + 128 + c];
                }
                const float mean = sm * inv_n;
                const float var = fmaxf(sq * inv_n - mean * mean, 0.f);
                const float rs = rsqrtf(var + BN_EPS);
                const float g  = md ? ((const float*)gammav)[gelem + c] : bf2f(((const u16*)gammav)[gelem + c]);
                const float be = md ? ((const float*)betav)[gelem + c]  : bf2f(((const u16*)betav)[gelem + c]);
                cA[j] = g * rs;
                cB[j] = be - cA[j] * mean;
            }
        }
        uint4 v[8];
        #pragma unroll
        for (int i = 0; i < 8; ++i) {
            const int gm = m0 + i * 16 + rbase;
            if (gm < N_NODES) v[i] = *reinterpret_cast<const uint4*>(A + (size_t)gm * HD + seg * 8);
            else { v[i].x = 0; v[i].y = 0; v[i].z = 0; v[i].w = 0; }
        }
        #pragma unroll
        for (int i = 0; i < 8; ++i) {
            uint4 o = v[i];
            if (TRANS) {
                u32 w[4] = {o.x, o.y, o.z, o.w};
                #pragma unroll
                for (int q = 0; q < 4; ++q) {
                    const float lo = lrelu(cA[2 * q] * bf2f_lo(w[q]) + cB[2 * q]);
                    const float hi = lrelu(cA[2 * q + 1] * bf2f_hi(w[q]) + cB[2 * q + 1]);
                    w[q] = pack2(lo, hi);
                }
                o.x = w[0]; o.y = w[1]; o.z = w[2]; o.w = w[3];
            }
            *reinterpret_cast<uint4*>(&Asm[i * 16 + rbase][seg * 8]) = o;
        }
    }
    __syncthreads();

    // ---- MFMA phase: A from LDS, W frags from L2 ----
    const int wave = tid >> 6, lane = tid & 63;
    const int quad = lane >> 4, lx = lane & 15;
    const int wrow0 = wave * 32;
    f32x4 acc[2][8] = {};
    #pragma unroll 2
    for (int kb = 0; kb < 4; ++kb) {
        bf16x8 bfr[8];
        #pragma unroll
        for (int nt = 0; nt < 8; ++nt)
            bfr[nt] = *reinterpret_cast<const bf16x8*>(wp + (((size_t)(kb * 8 + nt) * 64 + lane) << 3));
        const int k0 = kb * 32 + quad * 8;
        #pragma unroll
        for (int ms = 0; ms < 2; ++ms) {
            const bf16x8 af = *reinterpret_cast<const bf16x8*>(&Asm[wrow0 + ms * 16 + lx][k0]);
            #pragma unroll
            for (int nt = 0; nt < 8; ++nt)
                acc[ms][nt] = __builtin_amdgcn_mfma_f32_16x16x32_bf16(af, bfr[nt], acc[ms][nt], 0, 0, 0);
        }
    }
    __syncthreads();  // all waves finished reading Asm

    // ---- epilogue: bias + (stats) + write bf16 result back into Asm ----
    #pragma unroll
    for (int nt = 0; nt < 8; ++nt) {
        const int n = nt * 16 + lx;
        const float bj = md ? ((const float*)biasv)[belem + n] : bf2f(((const u16*)biasv)[belem + n]);
        float s = 0.f, q = 0.f;
        #pragma unroll
        for (int ms = 0; ms < 2; ++ms) {
            #pragma unroll
            for (int r = 0; r < 4; ++r) {
                const int lrow = wrow0 + ms * 16 + quad * 4 + r;
                const float v = acc[ms][nt][r] + bj;
                Asm[lrow][n] = f2bf(v);
                if (STATS && (m0 + lrow) < N_NODES) { s += v; q += v * v; }
            }
        }
        if (STATS) {
            s += __shfl_xor(s, 16); s += __shfl_xor(s, 32);
            q += __shfl_xor(q, 16); q += __shfl_xor(q, 32);
            if (quad == 0) { sred[wave][n] = s; sqred[wave][n] = q; }
        }
    }
    __syncthreads();

    // ---- coalesced uint4 store pass ----
    #pragma unroll
    for (int i = 0; i < 8; ++i) {
        const int row = i * 16 + rbase;
        const int gm = m0 + row;
        if (gm < N_NODES)
            *reinterpret_cast<uint4*>(out + (size_t)gm * HD + seg * 8) =
                *reinterpret_cast<const uint4*>(&Asm[row][seg * 8]);
    }

    if (STATS) {
        float* sdst = stats + (size_t)(blockIdx.x & (NREP - 1)) * 256;
        if (tid < 128) {
            atomicAdd(&sdst[tid], sred[0][tid] + sred[1][tid] + sred[2][tid] + sred[3][tid]);
        } else if (tid < 256) {
            const int c = tid - 128;
            atomicAdd(&sdst[128 + c], sqred[0][c] + sqred[1][c] + sqred[2][c] + sqred[3][c]);
        }
    }
}

// ---------------- pooling + head ----------------
__global__ __launch_bounds__(128) void pool_kernel(const u16* __restrict__ hf, const int* __restrict__ batch,
                                                   const int* __restrict__ mode, float* __restrict__ emb,
                                                   void* __restrict__ outv) {
    const int g = blockIdx.x;
    const int j = threadIdx.x;
    const int md = *mode;
    int lo = 0, hi = N_NODES;
    while (lo < hi) { int m = (lo + hi) >> 1; if (batch[m] < g) lo = m + 1; else hi = m; }
    const int s = lo;
    hi = N_NODES;
    while (lo < hi) { int m = (lo + hi) >> 1; if (batch[m] < g + 1) lo = m + 1; else hi = m; }
    const int e = lo;
    const int cnt = e - s;
    float sum = 0.f, mx = -INFINITY;
    for (int n = s; n < e; ++n) {
        float v = bf2f(hf[(size_t)n * HD + j]);
        sum += v;
        mx = fmaxf(mx, v);
    }
    float mean = sum / (float)max(cnt, 1);
    if (cnt == 0) mx = 0.f;
    emb[(size_t)g * 256 + j] = mean;
    emb[(size_t)g * 256 + 128 + j] = mx;
    const size_t base = (size_t)N_GRAPHS * 3 + (size_t)g * 256;
    if (md) {
        ((float*)outv)[base + j] = mean;
        ((float*)outv)[base + 128 + j] = mx;
    } else {
        ((u16*)outv)[base + j] = f2bf(mean);
        ((u16*)outv)[base + 128 + j] = f2bf(mx);
    }
}

__global__ __launch_bounds__(64) void final_kernel(const float* __restrict__ emb, const void* __restrict__ fcwv,
                                                   const void* __restrict__ fcbv, const void* __restrict__ fc2wv,
                                                   const void* __restrict__ fc2bv, const int* __restrict__ mode,
                                                   void* __restrict__ outv) {
    __shared__ float es[256];
    __shared__ float hs[64];
    const int g = blockIdx.x, t = threadIdx.x;
    const int md = *mode;
    reinterpret_cast<float4*>(es)[t] = reinterpret_cast<const float4*>(emb + (size_t)g * 256)[t];
    __syncthreads();
    float acc = md ? ((const float*)fcbv)[t] : bf2f(((const u16*)fcbv)[t]);
    if (md) {
        const float* w = (const float*)fcwv;
        #pragma unroll 8
        for (int k = 0; k < 256; ++k) acc += es[k] * w[k * 64 + t];
    } else {
        const u16* w = (const u16*)fcwv;
        #pragma unroll 8
        for (int k = 0; k < 256; ++k) acc += es[k] * bf2f(w[k * 64 + t]);
    }
    hs[t] = lrelu(acc);
    __syncthreads();
    if (t < 3) {
        float o = md ? ((const float*)fc2bv)[t] : bf2f(((const u16*)fc2bv)[t]);
        if (md) {
            const float* w = (const float*)fc2wv;
            #pragma unroll 8
            for (int j = 0; j < 64; ++j) o += hs[j] * w[j * 3 + t];
            ((float*)outv)[(size_t)g * 3 + t] = o;
        } else {
            const u16* w = (const u16*)fc2wv;
            #pragma unroll 8
            for (int j = 0; j < 64; ++j) o += hs[j] * bf2f(w[j * 3 + t]);
            ((u16*)outv)[(size_t)g * 3 + t] = f2bf(o);
        }
    }
}

// ---------------- launch ----------------
static inline size_t align256(size_t x) { return (x + 255) & ~(size_t)255; }

extern "C" void kernel_launch(void* const* d_in, const int* in_sizes, int n_in,
                              void* d_out, int out_size, void* d_ws, size_t ws_size,
                              hipStream_t stream) {
    (void)in_sizes; (void)n_in; (void)out_size; (void)ws_size;
    const void* x    = d_in[0];
    const void* W1a  = d_in[2];
    const void* W1b  = d_in[3];
    const void* b1   = d_in[4];
    const void* g1   = d_in[5];
    const void* be1  = d_in[6];
    const void* W2   = d_in[7];
    const void* b2   = d_in[8];
    const void* gn   = d_in[9];
    const void* bnb  = d_in[10];
    const void* fcw  = d_in[11];
    const void* fcb  = d_in[12];
    const void* fc2w = d_in[13];
    const void* fc2b = d_in[14];
    const int* ei    = (const int*)d_in[15];
    const int* batch = (const int*)d_in[16];

    char* p = (char*)d_ws;
    size_t off = 0;
    u16* zb = (u16*)(p + off); off += align256((size_t)N_NODES * HD * 2);
    u16* hb = (u16*)(p + off); off += align256((size_t)N_NODES * HD * 2);
    u16* wpack = (u16*)(p + off); off += align256((size_t)12 * HD * HD * 2);
    float* emb = (float*)(p + off); off += align256((size_t)N_GRAPHS * 256 * 4);
    int* row_ptr = (int*)(p + off); off += align256((size_t)(N_NODES + 1) * 4);
    int* cursor = (int*)(p + off); off += align256((size_t)N_NODES * 4);
    int* col_idx = (int*)(p + off); off += align256((size_t)N_EDGES * 4);
    int* bsum = (int*)(p + off); off += align256((size_t)SB * 4);
    float* statsAB = (float*)(p + off); off += align256((size_t)2 * NREP * 256 * 4);
    int* mode = (int*)(p + off); off += align256(4);
    float* statsA = statsAB;                 // NREP*256 floats
    float* statsB = statsAB + NREP * 256;    // NREP*256 floats

    const int EB = (N_EDGES + 255) / 256;
    const int AGB = (N_NODES + 15) / 16;     // 6250 (4 nodes/wave, 4 waves/block)
    const int GBM = (N_NODES + 127) / 128;   // 782

    detect_kernel<<<1, 256, 0, stream>>>((const u16*)x, mode);

    hipMemsetAsync(cursor, 0, (size_t)N_NODES * 4, stream);
    hist_kernel<<<EB, 256, 0, stream>>>(ei + N_EDGES, cursor);
    scan1_kernel<<<SB, 256, 0, stream>>>(cursor, bsum);
    scan2_kernel<<<1, 512, 0, stream>>>(bsum, row_ptr);
    scan3_kernel<<<SB, 256, 0, stream>>>(cursor, bsum, row_ptr);
    hipMemcpyAsync(cursor, row_ptr, (size_t)N_NODES * 4, hipMemcpyDeviceToDevice, stream);
    fill_kernel<<<EB, 256, 0, stream>>>(ei, ei + N_EDGES, cursor, col_idx);
    pack_w_kernel<<<96, 256, 0, stream>>>(W1a, W1b, W2, mode, wpack);

    u16* cur = zb;
    u16* oth = hb;
    for (int l = 0; l < NLAYERS; ++l) {
        if (l == 0) {
            agg0_kernel<<<AGB, 256, 0, stream>>>(x, row_ptr, col_idx, mode, cur);
        } else {
            agg_bn_kernel<<<AGB, 256, 0, stream>>>(cur, row_ptr, col_idx, statsB, gn, bnb,
                                                   (size_t)(l - 1) * HD, mode, oth);
            u16* t = cur; cur = oth; oth = t;
        }
        const size_t voff = (size_t)l * HD;
        hipMemsetAsync(statsAB, 0, (size_t)2 * NREP * 256 * 4, stream);  // after agg consumed statsB
        gemm_mfma<0, 1><<<GBM, 256, 0, stream>>>(cur, wpack + (size_t)l * HD * HD, b1, voff,
                                                 nullptr, g1, be1, voff, mode, cur, statsA);
        if (l < NLAYERS - 1) {
            gemm_mfma<1, 1><<<GBM, 256, 0, stream>>>(cur, wpack + (size_t)(6 + l) * HD * HD, b2, voff,
                                                     statsA, g1, be1, voff, mode, cur, statsB);
        } else {
            gemm_mfma<1, 0><<<GBM, 256, 0, stream>>>(cur, wpack + (size_t)(6 + l) * HD * HD, b2, voff,
                                                     statsA, g1, be1, voff, mode, cur, nullptr);
        }
    }

    pool_kernel<<<N_GRAPHS, 128, 0, stream>>>(cur, batch, mode, emb, d_out);
    final_kernel<<<N_GRAPHS, 64, 0, stream>>>(emb, fcw, fcb, fc2w, fc2b, mode, d_out);
}

// Round 7
// 709.875 us; speedup vs baseline: 1.6042x; 1.6042x over previous
//
#include <hip/hip_runtime.h>
#include <stdint.h>

#define N_NODES 100000
#define N_EDGES 400000
#define N_GRAPHS 2000
#define C_IN 48
#define HD 128
#define NLAYERS 6
#define BN_EPS 1e-5f
#define NSLOPE 0.01f
#define SB 391   // ceil(N_NODES/256)
#define NREP 8   // stats replication factor

typedef uint16_t u16;
typedef uint32_t u32;
typedef short bf16x8 __attribute__((ext_vector_type(8)));
typedef float f32x4 __attribute__((ext_vector_type(4)));

__device__ __forceinline__ float bf2f_lo(u32 v) { return __uint_as_float(v << 16); }
__device__ __forceinline__ float bf2f_hi(u32 v) { return __uint_as_float(v & 0xffff0000u); }
__device__ __forceinline__ float bf2f(u16 h) { return __uint_as_float(((u32)h) << 16); }
__device__ __forceinline__ u16 f2bf(float f) {
    u32 u = __float_as_uint(f);
    u32 r = (u + 0x7fffu + ((u >> 16) & 1u)) >> 16;
    return (u16)r;
}
__device__ __forceinline__ u32 pack2(float a, float b) {
    return (u32)f2bf(a) | ((u32)f2bf(b) << 16);
}
__device__ __forceinline__ float lrelu(float v) { return v >= 0.f ? v : v * NSLOPE; }

// dtype detection: mode=1 -> float inputs are fp32; mode=0 -> bf16.
__global__ __launch_bounds__(256) void detect_kernel(const u16* __restrict__ x, int* __restrict__ mode) {
    __shared__ int flag;
    if (threadIdx.x == 0) flag = 0;
    __syncthreads();
    int local = 0;
    for (int i = threadIdx.x; i < 16384; i += 256) {
        float a = fabsf(bf2f(x[i]));
        if (!(a < 1e4f)) local = 1;
    }
    if (local) flag = 1;
    __syncthreads();
    if (threadIdx.x == 0) mode[0] = flag;
}

// ---------------- CSR build ----------------
__global__ __launch_bounds__(256) void hist_kernel(const int* __restrict__ dst, int* __restrict__ cnt) {
    int e = blockIdx.x * 256 + threadIdx.x;
    if (e < N_EDGES) atomicAdd(&cnt[dst[e]], 1);
}

__global__ __launch_bounds__(256) void scan1_kernel(const int* __restrict__ cnt, int* __restrict__ bsum) {
    __shared__ int s[256];
    const int t = threadIdx.x;
    const int i = blockIdx.x * 256 + t;
    s[t] = (i < N_NODES) ? cnt[i] : 0;
    __syncthreads();
    for (int d = 128; d > 0; d >>= 1) {
        if (t < d) s[t] += s[t + d];
        __syncthreads();
    }
    if (t == 0) bsum[blockIdx.x] = s[0];
}

__global__ __launch_bounds__(512) void scan2_kernel(int* __restrict__ bsum, int* __restrict__ row_ptr) {
    __shared__ int s[SB];
    const int t = threadIdx.x;
    if (t < SB) s[t] = bsum[t];
    __syncthreads();
    if (t == 0) {
        int run = 0;
        for (int b = 0; b < SB; ++b) { int v = s[b]; s[b] = run; run += v; }
        row_ptr[0] = 0;
    }
    __syncthreads();
    if (t < SB) bsum[t] = s[t];
}

__global__ __launch_bounds__(256) void scan3_kernel(const int* __restrict__ cnt, const int* __restrict__ bsum,
                                                    int* __restrict__ row_ptr) {
    __shared__ int s[256];
    const int t = threadIdx.x;
    const int i = blockIdx.x * 256 + t;
    s[t] = (i < N_NODES) ? cnt[i] : 0;
    __syncthreads();
    if (t == 0) {
        int run = bsum[blockIdx.x];
        for (int j = 0; j < 256; ++j) { run += s[j]; s[j] = run; }
    }
    __syncthreads();
    if (i < N_NODES) row_ptr[i + 1] = s[t];
}

__global__ __launch_bounds__(256) void fill_kernel(const int* __restrict__ src, const int* __restrict__ dst,
                                                   int* __restrict__ cursor, int* __restrict__ col_idx) {
    int e = blockIdx.x * 256 + threadIdx.x;
    if (e < N_EDGES) {
        int d = dst[e];
        int slot = atomicAdd(&cursor[d], 1);
        col_idx[slot] = src[e];
    }
}

// ---------------- weight pre-pack into MFMA B-fragment layout (bf16) ----------------
__global__ __launch_bounds__(256) void pack_w_kernel(const void* __restrict__ W1a, const void* __restrict__ W1b,
                                                     const void* __restrict__ W2, const int* __restrict__ mode,
                                                     u16* __restrict__ wpack) {
    const int t = blockIdx.x * 256 + threadIdx.x;  // 12*2048 = 24576
    if (t >= 24576) return;
    const int mat = t >> 11;
    const int r = t & 2047;
    const int l = r & 63;
    const int f = r >> 6;
    const int kb = f >> 3, nt = f & 7;
    const int k0 = kb * 32 + (l >> 4) * 8;
    const int n = nt * 16 + (l & 15);
    const int md = *mode;
    u16 vals[8];
    #pragma unroll
    for (int j = 0; j < 8; ++j) {
        const int k = k0 + j;
        float v;
        if (mat == 0) {
            v = (k < C_IN) ? (md ? ((const float*)W1a)[k * HD + n] : bf2f(((const u16*)W1a)[k * HD + n])) : 0.f;
        } else if (mat < 6) {
            const size_t o = (size_t)(mat - 1) * HD * HD + (size_t)k * HD + n;
            v = md ? ((const float*)W1b)[o] : bf2f(((const u16*)W1b)[o]);
        } else {
            const size_t o = (size_t)(mat - 6) * HD * HD + (size_t)k * HD + n;
            v = md ? ((const float*)W2)[o] : bf2f(((const u16*)W2)[o]);
        }
        vals[j] = f2bf(v);
    }
    uint4 o;
    o.x = (u32)vals[0] | ((u32)vals[1] << 16);
    o.y = (u32)vals[2] | ((u32)vals[3] << 16);
    o.z = (u32)vals[4] | ((u32)vals[5] << 16);
    o.w = (u32)vals[6] | ((u32)vals[7] << 16);
    *reinterpret_cast<uint4*>(wpack + (size_t)t * 8) = o;
}

// ---------------- bias pre-pack to f32 ----------------
__global__ __launch_bounds__(256) void pack_b_kernel(const void* __restrict__ b1, const void* __restrict__ b2,
                                                     const int* __restrict__ mode, float* __restrict__ biasf) {
    const int i = blockIdx.x * 256 + threadIdx.x;  // 12*128
    if (i >= 12 * HD) return;
    const int mat = i >> 7, c = i & 127;
    const int md = *mode;
    float v;
    if (mat < 6) v = md ? ((const float*)b1)[mat * HD + c] : bf2f(((const u16*)b1)[mat * HD + c]);
    else         v = md ? ((const float*)b2)[(mat - 6) * HD + c] : bf2f(((const u16*)b2)[(mat - 6) * HD + c]);
    biasf[i] = v;
}

// ---------------- BN finalize: replicated raw stats -> coef[256] = {A[128], B[128]} ----------------
__global__ __launch_bounds__(128) void finalize_kernel(const float* __restrict__ stats,
                                                       const void* __restrict__ gammav, const void* __restrict__ betav,
                                                       size_t elem, const int* __restrict__ mode,
                                                       float* __restrict__ coef) {
    const int j = threadIdx.x;
    const int md = *mode;
    float sm = 0.f, sq = 0.f;
    #pragma unroll
    for (int rep = 0; rep < NREP; ++rep) {
        sm += stats[rep * 256 + j];
        sq += stats[rep * 256 + 128 + j];
    }
    const float inv_n = 1.0f / (float)N_NODES;
    const float mean = sm * inv_n;
    const float var = fmaxf(sq * inv_n - mean * mean, 0.f);
    const float rs = rsqrtf(var + BN_EPS);
    const float g  = md ? ((const float*)gammav)[elem + j] : bf2f(((const u16*)gammav)[elem + j]);
    const float be = md ? ((const float*)betav)[elem + j]  : bf2f(((const u16*)betav)[elem + j]);
    const float A = g * rs;
    coef[j] = A;
    coef[128 + j] = be - A * mean;
}

// ---------------- agg0: 2 nodes/wave (half-wave each), unroll-2 gather ----------------
__global__ __launch_bounds__(256) void agg0_kernel(const void* __restrict__ xv, const int* __restrict__ row_ptr,
                                                   const int* __restrict__ col_idx, const int* __restrict__ mode,
                                                   u16* __restrict__ z) {
    const int wave = threadIdx.x >> 6, lane = threadIdx.x & 63;
    const int half = lane >> 5, hl = lane & 31;
    const int node = blockIdx.x * 8 + wave * 2 + half;
    const bool valid = node < N_NODES;
    const int md = *mode;
    int s = 0, deg = 0;
    if (valid) { s = row_ptr[node]; deg = row_ptr[node + 1] - s; }
    float a0 = 0.f, a1 = 0.f;
    if (md) {
        const float* xf = (const float*)xv;
        if (valid && hl < 24) {
            float2 v = *reinterpret_cast<const float2*>(xf + (size_t)node * C_IN + 2 * hl);
            a0 = v.x; a1 = v.y;
        }
        for (int i = 0; i < deg; i += 2) {
            const int id0 = col_idx[s + i];
            const bool h1 = (i + 1) < deg;
            const int id1 = h1 ? col_idx[s + i + 1] : 0;
            if (hl < 24) {
                float2 w0 = *reinterpret_cast<const float2*>(xf + (size_t)id0 * C_IN + 2 * hl);
                float2 w1 = make_float2(0.f, 0.f);
                if (h1) w1 = *reinterpret_cast<const float2*>(xf + (size_t)id1 * C_IN + 2 * hl);
                a0 += w0.x + w1.x; a1 += w0.y + w1.y;
            }
        }
    } else {
        const u16* xh = (const u16*)xv;
        if (valid && hl < 24) {
            u32 v = *reinterpret_cast<const u32*>(xh + (size_t)node * C_IN + 2 * hl);
            a0 = bf2f_lo(v); a1 = bf2f_hi(v);
        }
        for (int i = 0; i < deg; i += 2) {
            const int id0 = col_idx[s + i];
            const bool h1 = (i + 1) < deg;
            const int id1 = h1 ? col_idx[s + i + 1] : 0;
            if (hl < 24) {
                u32 w0 = *reinterpret_cast<const u32*>(xh + (size_t)id0 * C_IN + 2 * hl);
                u32 w1 = 0;
                if (h1) w1 = *reinterpret_cast<const u32*>(xh + (size_t)id1 * C_IN + 2 * hl);
                a0 += bf2f_lo(w0) + bf2f_lo(w1);
                a1 += bf2f_hi(w0) + bf2f_hi(w1);
            }
        }
    }
    if (valid) {
        const u32 w = (hl < 24) ? pack2(a0, a1) : 0u;
        *reinterpret_cast<u32*>(z + (size_t)node * HD + 2 * hl) = w;           // cols 0..63
        *reinterpret_cast<u32*>(z + (size_t)node * HD + 64 + 2 * hl) = 0u;     // cols 64..127
    }
}

// ---------------- agg_bn: quarter-wave/node, uint4 rows, precomputed coefs ----------------
__global__ __launch_bounds__(256) void agg_bn_kernel(const u16* __restrict__ u, const int* __restrict__ row_ptr,
                                                     const int* __restrict__ col_idx,
                                                     const float* __restrict__ coef, u16* __restrict__ z) {
    const int wave = threadIdx.x >> 6, lane = threadIdx.x & 63;
    const int q = lane >> 4, c = lane & 15;
    const int node = blockIdx.x * 16 + wave * 4 + q;
    const bool valid = node < N_NODES;
    float cA[8], cB[8];
    #pragma unroll
    for (int j = 0; j < 8; ++j) {
        cA[j] = coef[c * 8 + j];
        cB[j] = coef[128 + c * 8 + j];
    }
    int s = 0, deg = 0;
    if (valid) { s = row_ptr[node]; deg = row_ptr[node + 1] - s; }
    float a[8];
    #pragma unroll
    for (int j = 0; j < 8; ++j) a[j] = 0.f;
    if (valid) {
        const uint4 v = *reinterpret_cast<const uint4*>(u + (size_t)node * HD + c * 8);
        const u32 w[4] = {v.x, v.y, v.z, v.w};
        #pragma unroll
        for (int p = 0; p < 4; ++p) {
            a[2 * p]     = lrelu(cA[2 * p] * bf2f_lo(w[p]) + cB[2 * p]);
            a[2 * p + 1] = lrelu(cA[2 * p + 1] * bf2f_hi(w[p]) + cB[2 * p + 1]);
        }
    }
    for (int i = 0; i < deg; i += 2) {
        const int id0 = col_idx[s + i];
        const bool h1 = (i + 1) < deg;
        const int id1 = h1 ? col_idx[s + i + 1] : 0;
        const uint4 r0 = *reinterpret_cast<const uint4*>(u + (size_t)id0 * HD + c * 8);
        uint4 r1; r1.x = r1.y = r1.z = r1.w = 0;
        if (h1) r1 = *reinterpret_cast<const uint4*>(u + (size_t)id1 * HD + c * 8);
        const u32 w0[4] = {r0.x, r0.y, r0.z, r0.w};
        const u32 w1[4] = {r1.x, r1.y, r1.z, r1.w};
        #pragma unroll
        for (int p = 0; p < 4; ++p) {
            a[2 * p]     += lrelu(cA[2 * p] * bf2f_lo(w0[p]) + cB[2 * p]);
            a[2 * p + 1] += lrelu(cA[2 * p + 1] * bf2f_hi(w0[p]) + cB[2 * p + 1]);
            if (h1) {
                a[2 * p]     += lrelu(cA[2 * p] * bf2f_lo(w1[p]) + cB[2 * p]);
                a[2 * p + 1] += lrelu(cA[2 * p + 1] * bf2f_hi(w1[p]) + cB[2 * p + 1]);
            }
        }
    }
    if (valid) {
        uint4 o;
        o.x = pack2(a[0], a[1]); o.y = pack2(a[2], a[3]);
        o.z = pack2(a[4], a[5]); o.w = pack2(a[6], a[7]);
        *reinterpret_cast<uint4*>(z + (size_t)node * HD + c * 8) = o;
    }
}

// ---------------- MFMA GEMM: BM=64, LDS A-stage (1 barrier), direct-store epilogue ----------------
// TRANS applies lrelu(cA*x+cB) (coef precomputed) while staging; STATS accumulates per-column
// sum/sumsq into NREP-replicated stats. IN-PLACE SAFE (out == A).
template <int TRANS, int STATS>
__global__ __launch_bounds__(256) void gemm_mfma(const u16* A, const u16* __restrict__ wp,
                                                 const float* __restrict__ biasf,
                                                 const float* __restrict__ coef,
                                                 u16* out, float* __restrict__ stats) {
    __shared__ u16 Asm[64][136];
    __shared__ float sred[4][128];
    __shared__ float sqred[4][128];
    const int tid = threadIdx.x;
    const int m0 = blockIdx.x * 64;
    const int rrow = tid >> 4;   // 0..15
    const int seg = tid & 15;    // cols seg*8..seg*8+7

    // ---- stage A tile (+ optional BN+lrelu): 4 uint4 loads/thread ----
    {
        float cA[8], cB[8];
        if (TRANS) {
            #pragma unroll
            for (int j = 0; j < 8; ++j) {
                cA[j] = coef[seg * 8 + j];
                cB[j] = coef[128 + seg * 8 + j];
            }
        }
        uint4 v[4];
        #pragma unroll
        for (int i = 0; i < 4; ++i) {
            const int gm = m0 + i * 16 + rrow;
            if (gm < N_NODES) v[i] = *reinterpret_cast<const uint4*>(A + (size_t)gm * HD + seg * 8);
            else { v[i].x = 0; v[i].y = 0; v[i].z = 0; v[i].w = 0; }
        }
        #pragma unroll
        for (int i = 0; i < 4; ++i) {
            uint4 o = v[i];
            if (TRANS) {
                u32 w[4] = {o.x, o.y, o.z, o.w};
                #pragma unroll
                for (int p = 0; p < 4; ++p) {
                    const float lo = lrelu(cA[2 * p] * bf2f_lo(w[p]) + cB[2 * p]);
                    const float hi = lrelu(cA[2 * p + 1] * bf2f_hi(w[p]) + cB[2 * p + 1]);
                    w[p] = pack2(lo, hi);
                }
                o.x = w[0]; o.y = w[1]; o.z = w[2]; o.w = w[3];
            }
            *reinterpret_cast<uint4*>(&Asm[i * 16 + rrow][seg * 8]) = o;
        }
    }
    __syncthreads();

    // ---- MFMA: 16 rows/wave; A frags from LDS, W frags from L2 ----
    const int wave = tid >> 6, lane = tid & 63;
    const int quad = lane >> 4, lx = lane & 15;
    f32x4 acc[8] = {};
    #pragma unroll 2
    for (int kb = 0; kb < 4; ++kb) {
        bf16x8 bfr[8];
        #pragma unroll
        for (int nt = 0; nt < 8; ++nt)
            bfr[nt] = *reinterpret_cast<const bf16x8*>(wp + (((size_t)(kb * 8 + nt) * 64 + lane) << 3));
        const bf16x8 af = *reinterpret_cast<const bf16x8*>(&Asm[wave * 16 + lx][kb * 32 + quad * 8]);
        #pragma unroll
        for (int nt = 0; nt < 8; ++nt)
            acc[nt] = __builtin_amdgcn_mfma_f32_16x16x32_bf16(af, bfr[nt], acc[nt], 0, 0, 0);
    }

    // ---- epilogue: bias + direct u16 stores + optional stats ----
    const int mrow0 = m0 + wave * 16;
    #pragma unroll
    for (int nt = 0; nt < 8; ++nt) {
        const int n = nt * 16 + lx;
        const float bj = biasf[n];
        float s = 0.f, q = 0.f;
        #pragma unroll
        for (int r = 0; r < 4; ++r) {
            const int m = mrow0 + quad * 4 + r;
            if (m < N_NODES) {
                const float v = acc[nt][r] + bj;
                out[(size_t)m * HD + n] = f2bf(v);
                if (STATS) { s += v; q += v * v; }
            }
        }
        if (STATS) {
            s += __shfl_xor(s, 16); s += __shfl_xor(s, 32);
            q += __shfl_xor(q, 16); q += __shfl_xor(q, 32);
            if (quad == 0) { sred[wave][n] = s; sqred[wave][n] = q; }
        }
    }
    if (STATS) {
        __syncthreads();
        float* sdst = stats + (size_t)(blockIdx.x & (NREP - 1)) * 256;
        if (tid < 128) {
            atomicAdd(&sdst[tid], sred[0][tid] + sred[1][tid] + sred[2][tid] + sred[3][tid]);
        } else if (tid < 256) {
            const int c2 = tid - 128;
            atomicAdd(&sdst[128 + c2], sqred[0][c2] + sqred[1][c2] + sqred[2][c2] + sqred[3][c2]);
        }
    }
}

// ---------------- pooling + head ----------------
__global__ __launch_bounds__(128) void pool_kernel(const u16* __restrict__ hf, const int* __restrict__ batch,
                                                   const int* __restrict__ mode, float* __restrict__ emb,
                                                   void* __restrict__ outv) {
    const int g = blockIdx.x;
    const int j = threadIdx.x;
    const int md = *mode;
    int lo = 0, hi = N_NODES;
    while (lo < hi) { int m = (lo + hi) >> 1; if (batch[m] < g) lo = m + 1; else hi = m; }
    const int s = lo;
    hi = N_NODES;
    while (lo < hi) { int m = (lo + hi) >> 1; if (batch[m] < g + 1) lo = m + 1; else hi = m; }
    const int e = lo;
    const int cnt = e - s;
    float sum = 0.f, mx = -INFINITY;
    for (int n = s; n < e; ++n) {
        float v = bf2f(hf[(size_t)n * HD + j]);
        sum += v;
        mx = fmaxf(mx, v);
    }
    float mean = sum / (float)max(cnt, 1);
    if (cnt == 0) mx = 0.f;
    emb[(size_t)g * 256 + j] = mean;
    emb[(size_t)g * 256 + 128 + j] = mx;
    const size_t base = (size_t)N_GRAPHS * 3 + (size_t)g * 256;
    if (md) {
        ((float*)outv)[base + j] = mean;
        ((float*)outv)[base + 128 + j] = mx;
    } else {
        ((u16*)outv)[base + j] = f2bf(mean);
        ((u16*)outv)[base + 128 + j] = f2bf(mx);
    }
}

__global__ __launch_bounds__(64) void final_kernel(const float* __restrict__ emb, const void* __restrict__ fcwv,
                                                   const void* __restrict__ fcbv, const void* __restrict__ fc2wv,
                                                   const void* __restrict__ fc2bv, const int* __restrict__ mode,
                                                   void* __restrict__ outv) {
    __shared__ float es[256];
    __shared__ float hs[64];
    const int g = blockIdx.x, t = threadIdx.x;
    const int md = *mode;
    reinterpret_cast<float4*>(es)[t] = reinterpret_cast<const float4*>(emb + (size_t)g * 256)[t];
    __syncthreads();
    float acc = md ? ((const float*)fcbv)[t] : bf2f(((const u16*)fcbv)[t]);
    if (md) {
        const float* w = (const float*)fcwv;
        #pragma unroll 8
        for (int k = 0; k < 256; ++k) acc += es[k] * w[k * 64 + t];
    } else {
        const u16* w = (const u16*)fcwv;
        #pragma unroll 8
        for (int k = 0; k < 256; ++k) acc += es[k] * bf2f(w[k * 64 + t]);
    }
    hs[t] = lrelu(acc);
    __syncthreads();
    if (t < 3) {
        float o = md ? ((const float*)fc2bv)[t] : bf2f(((const u16*)fc2bv)[t]);
        if (md) {
            const float* w = (const float*)fc2wv;
            #pragma unroll 8
            for (int j = 0; j < 64; ++j) o += hs[j] * w[j * 3 + t];
            ((float*)outv)[(size_t)g * 3 + t] = o;
        } else {
            const u16* w = (const u16*)fc2wv;
            #pragma unroll 8
            for (int j = 0; j < 64; ++j) o += hs[j] * bf2f(w[j * 3 + t]);
            ((u16*)outv)[(size_t)g * 3 + t] = f2bf(o);
        }
    }
}

// ---------------- launch ----------------
static inline size_t align256(size_t x) { return (x + 255) & ~(size_t)255; }

extern "C" void kernel_launch(void* const* d_in, const int* in_sizes, int n_in,
                              void* d_out, int out_size, void* d_ws, size_t ws_size,
                              hipStream_t stream) {
    (void)in_sizes; (void)n_in; (void)out_size; (void)ws_size;
    const void* x    = d_in[0];
    const void* W1a  = d_in[2];
    const void* W1b  = d_in[3];
    const void* b1   = d_in[4];
    const void* g1   = d_in[5];
    const void* be1  = d_in[6];
    const void* W2   = d_in[7];
    const void* b2   = d_in[8];
    const void* gn   = d_in[9];
    const void* bnb  = d_in[10];
    const void* fcw  = d_in[11];
    const void* fcb  = d_in[12];
    const void* fc2w = d_in[13];
    const void* fc2b = d_in[14];
    const int* ei    = (const int*)d_in[15];
    const int* batch = (const int*)d_in[16];

    char* p = (char*)d_ws;
    size_t off = 0;
    u16* zb = (u16*)(p + off); off += align256((size_t)N_NODES * HD * 2);
    u16* hb = (u16*)(p + off); off += align256((size_t)N_NODES * HD * 2);
    u16* wpack = (u16*)(p + off); off += align256((size_t)12 * HD * HD * 2);
    float* biasf = (float*)(p + off); off += align256((size_t)12 * HD * 4);
    float* emb = (float*)(p + off); off += align256((size_t)N_GRAPHS * 256 * 4);
    int* row_ptr = (int*)(p + off); off += align256((size_t)(N_NODES + 1) * 4);
    int* cursor = (int*)(p + off); off += align256((size_t)N_NODES * 4);
    int* col_idx = (int*)(p + off); off += align256((size_t)N_EDGES * 4);
    int* bsum = (int*)(p + off); off += align256((size_t)SB * 4);
    float* statsAB = (float*)(p + off); off += align256((size_t)2 * NREP * 256 * 4);
    float* coefA = (float*)(p + off); off += align256(256 * 4);
    float* coefB = (float*)(p + off); off += align256(256 * 4);
    int* mode = (int*)(p + off); off += align256(4);
    float* statsA = statsAB;
    float* statsB = statsAB + NREP * 256;

    const int EB = (N_EDGES + 255) / 256;
    const int AG0 = (N_NODES + 7) / 8;       // 12500 (2 nodes/wave)
    const int AGB = (N_NODES + 15) / 16;     // 6250  (4 nodes/wave)
    const int GBM = (N_NODES + 63) / 64;     // 1563

    detect_kernel<<<1, 256, 0, stream>>>((const u16*)x, mode);

    hipMemsetAsync(cursor, 0, (size_t)N_NODES * 4, stream);
    hist_kernel<<<EB, 256, 0, stream>>>(ei + N_EDGES, cursor);
    scan1_kernel<<<SB, 256, 0, stream>>>(cursor, bsum);
    scan2_kernel<<<1, 512, 0, stream>>>(bsum, row_ptr);
    scan3_kernel<<<SB, 256, 0, stream>>>(cursor, bsum, row_ptr);
    hipMemcpyAsync(cursor, row_ptr, (size_t)N_NODES * 4, hipMemcpyDeviceToDevice, stream);
    fill_kernel<<<EB, 256, 0, stream>>>(ei, ei + N_EDGES, cursor, col_idx);
    pack_w_kernel<<<96, 256, 0, stream>>>(W1a, W1b, W2, mode, wpack);
    pack_b_kernel<<<6, 256, 0, stream>>>(b1, b2, mode, biasf);

    u16* cur = zb;
    u16* oth = hb;
    for (int l = 0; l < NLAYERS; ++l) {
        if (l == 0) {
            agg0_kernel<<<AG0, 256, 0, stream>>>(x, row_ptr, col_idx, mode, cur);
        } else {
            agg_bn_kernel<<<AGB, 256, 0, stream>>>(cur, row_ptr, col_idx, coefB, oth);
            u16* t = cur; cur = oth; oth = t;
        }
        hipMemsetAsync(statsAB, 0, (size_t)2 * NREP * 256 * 4, stream);
        gemm_mfma<0, 1><<<GBM, 256, 0, stream>>>(cur, wpack + (size_t)l * HD * HD,
                                                 biasf + (size_t)l * HD, nullptr, cur, statsA);
        finalize_kernel<<<1, 128, 0, stream>>>(statsA, g1, be1, (size_t)l * HD, mode, coefA);
        if (l < NLAYERS - 1) {
            gemm_mfma<1, 1><<<GBM, 256, 0, stream>>>(cur, wpack + (size_t)(6 + l) * HD * HD,
                                                     biasf + (size_t)(6 + l) * HD, coefA, cur, statsB);
            finalize_kernel<<<1, 128, 0, stream>>>(statsB, gn, bnb, (size_t)l * HD, mode, coefB);
        } else {
            gemm_mfma<1, 0><<<GBM, 256, 0, stream>>>(cur, wpack + (size_t)(6 + l) * HD * HD,
                                                     biasf + (size_t)(6 + l) * HD, coefA, cur, nullptr);
        }
    }

    pool_kernel<<<N_GRAPHS, 128, 0, stream>>>(cur, batch, mode, emb, d_out);
    final_kernel<<<N_GRAPHS, 64, 0, stream>>>(emb, fcw, fcb, fc2w, fc2b, mode, d_out);
}

// Round 8
// 687.134 us; speedup vs baseline: 1.6573x; 1.0331x over previous
//
#include <hip/hip_runtime.h>
#include <stdint.h>

#define N_NODES 100000
#define N_EDGES 400000
#define N_GRAPHS 2000
#define C_IN 48
#define HD 128
#define NLAYERS 6
#define BN_EPS 1e-5f
#define NSLOPE 0.01f
#define SB 391   // ceil(N_NODES/256)
#define NREP 8   // stats replication factor

typedef uint16_t u16;
typedef uint32_t u32;
typedef short bf16x8 __attribute__((ext_vector_type(8)));
typedef float f32x4 __attribute__((ext_vector_type(4)));

__device__ __forceinline__ float bf2f_lo(u32 v) { return __uint_as_float(v << 16); }
__device__ __forceinline__ float bf2f_hi(u32 v) { return __uint_as_float(v & 0xffff0000u); }
__device__ __forceinline__ float bf2f(u16 h) { return __uint_as_float(((u32)h) << 16); }
__device__ __forceinline__ u16 f2bf(float f) {
    u32 u = __float_as_uint(f);
    u32 r = (u + 0x7fffu + ((u >> 16) & 1u)) >> 16;
    return (u16)r;
}
__device__ __forceinline__ u32 pack2(float a, float b) {
    return (u32)f2bf(a) | ((u32)f2bf(b) << 16);
}
__device__ __forceinline__ float lrelu(float v) { return v >= 0.f ? v : v * NSLOPE; }

// dtype detection: mode=1 -> float inputs are fp32; mode=0 -> bf16.
__global__ __launch_bounds__(256) void detect_kernel(const u16* __restrict__ x, int* __restrict__ mode) {
    __shared__ int flag;
    if (threadIdx.x == 0) flag = 0;
    __syncthreads();
    int local = 0;
    for (int i = threadIdx.x; i < 16384; i += 256) {
        float a = fabsf(bf2f(x[i]));
        if (!(a < 1e4f)) local = 1;
    }
    if (local) flag = 1;
    __syncthreads();
    if (threadIdx.x == 0) mode[0] = flag;
}

// ---------------- CSR build ----------------
__global__ __launch_bounds__(256) void hist_kernel(const int* __restrict__ dst, int* __restrict__ cnt) {
    int e = blockIdx.x * 256 + threadIdx.x;
    if (e < N_EDGES) atomicAdd(&cnt[dst[e]], 1);
}

__global__ __launch_bounds__(256) void scan1_kernel(const int* __restrict__ cnt, int* __restrict__ bsum) {
    __shared__ int s[256];
    const int t = threadIdx.x;
    const int i = blockIdx.x * 256 + t;
    s[t] = (i < N_NODES) ? cnt[i] : 0;
    __syncthreads();
    for (int d = 128; d > 0; d >>= 1) {
        if (t < d) s[t] += s[t + d];
        __syncthreads();
    }
    if (t == 0) bsum[blockIdx.x] = s[0];
}

__global__ __launch_bounds__(512) void scan2_kernel(int* __restrict__ bsum, int* __restrict__ row_ptr) {
    __shared__ int s[SB];
    const int t = threadIdx.x;
    if (t < SB) s[t] = bsum[t];
    __syncthreads();
    if (t == 0) {
        int run = 0;
        for (int b = 0; b < SB; ++b) { int v = s[b]; s[b] = run; run += v; }
        row_ptr[0] = 0;
    }
    __syncthreads();
    if (t < SB) bsum[t] = s[t];
}

__global__ __launch_bounds__(256) void scan3_kernel(const int* __restrict__ cnt, const int* __restrict__ bsum,
                                                    int* __restrict__ row_ptr) {
    __shared__ int s[256];
    const int t = threadIdx.x;
    const int i = blockIdx.x * 256 + t;
    s[t] = (i < N_NODES) ? cnt[i] : 0;
    __syncthreads();
    if (t == 0) {
        int run = bsum[blockIdx.x];
        for (int j = 0; j < 256; ++j) { run += s[j]; s[j] = run; }
    }
    __syncthreads();
    if (i < N_NODES) row_ptr[i + 1] = s[t];
}

__global__ __launch_bounds__(256) void fill_kernel(const int* __restrict__ src, const int* __restrict__ dst,
                                                   int* __restrict__ cursor, int* __restrict__ col_idx) {
    int e = blockIdx.x * 256 + threadIdx.x;
    if (e < N_EDGES) {
        int d = dst[e];
        int slot = atomicAdd(&cursor[d], 1);
        col_idx[slot] = src[e];
    }
}

// ---------------- weight pre-pack into MFMA B-fragment layout (bf16) ----------------
__global__ __launch_bounds__(256) void pack_w_kernel(const void* __restrict__ W1a, const void* __restrict__ W1b,
                                                     const void* __restrict__ W2, const int* __restrict__ mode,
                                                     u16* __restrict__ wpack) {
    const int t = blockIdx.x * 256 + threadIdx.x;  // 12*2048 = 24576
    if (t >= 24576) return;
    const int mat = t >> 11;
    const int r = t & 2047;
    const int l = r & 63;
    const int f = r >> 6;
    const int kb = f >> 3, nt = f & 7;
    const int k0 = kb * 32 + (l >> 4) * 8;
    const int n = nt * 16 + (l & 15);
    const int md = *mode;
    u16 vals[8];
    #pragma unroll
    for (int j = 0; j < 8; ++j) {
        const int k = k0 + j;
        float v;
        if (mat == 0) {
            v = (k < C_IN) ? (md ? ((const float*)W1a)[k * HD + n] : bf2f(((const u16*)W1a)[k * HD + n])) : 0.f;
        } else if (mat < 6) {
            const size_t o = (size_t)(mat - 1) * HD * HD + (size_t)k * HD + n;
            v = md ? ((const float*)W1b)[o] : bf2f(((const u16*)W1b)[o]);
        } else {
            const size_t o = (size_t)(mat - 6) * HD * HD + (size_t)k * HD + n;
            v = md ? ((const float*)W2)[o] : bf2f(((const u16*)W2)[o]);
        }
        vals[j] = f2bf(v);
    }
    uint4 o;
    o.x = (u32)vals[0] | ((u32)vals[1] << 16);
    o.y = (u32)vals[2] | ((u32)vals[3] << 16);
    o.z = (u32)vals[4] | ((u32)vals[5] << 16);
    o.w = (u32)vals[6] | ((u32)vals[7] << 16);
    *reinterpret_cast<uint4*>(wpack + (size_t)t * 8) = o;
}

// ---------------- bias pre-pack to f32 ----------------
__global__ __launch_bounds__(256) void pack_b_kernel(const void* __restrict__ b1, const void* __restrict__ b2,
                                                     const int* __restrict__ mode, float* __restrict__ biasf) {
    const int i = blockIdx.x * 256 + threadIdx.x;  // 12*128
    if (i >= 12 * HD) return;
    const int mat = i >> 7, c = i & 127;
    const int md = *mode;
    float v;
    if (mat < 6) v = md ? ((const float*)b1)[mat * HD + c] : bf2f(((const u16*)b1)[mat * HD + c]);
    else         v = md ? ((const float*)b2)[(mat - 6) * HD + c] : bf2f(((const u16*)b2)[(mat - 6) * HD + c]);
    biasf[i] = v;
}

// ---------------- BN finalize: replicated raw stats -> coef[256] = {A[128], B[128]} ----------------
__global__ __launch_bounds__(128) void finalize_kernel(const float* __restrict__ stats,
                                                       const void* __restrict__ gammav, const void* __restrict__ betav,
                                                       size_t elem, const int* __restrict__ mode,
                                                       float* __restrict__ coef) {
    const int j = threadIdx.x;
    const int md = *mode;
    float sm = 0.f, sq = 0.f;
    #pragma unroll
    for (int rep = 0; rep < NREP; ++rep) {
        sm += stats[rep * 256 + j];
        sq += stats[rep * 256 + 128 + j];
    }
    const float inv_n = 1.0f / (float)N_NODES;
    const float mean = sm * inv_n;
    const float var = fmaxf(sq * inv_n - mean * mean, 0.f);
    const float rs = rsqrtf(var + BN_EPS);
    const float g  = md ? ((const float*)gammav)[elem + j] : bf2f(((const u16*)gammav)[elem + j]);
    const float be = md ? ((const float*)betav)[elem + j]  : bf2f(((const u16*)betav)[elem + j]);
    const float A = g * rs;
    coef[j] = A;
    coef[128 + j] = be - A * mean;
}

// ---------------- agg0: 2 nodes/wave (half-wave each), unroll-2 gather ----------------
__global__ __launch_bounds__(256) void agg0_kernel(const void* __restrict__ xv, const int* __restrict__ row_ptr,
                                                   const int* __restrict__ col_idx, const int* __restrict__ mode,
                                                   u16* __restrict__ z) {
    const int wave = threadIdx.x >> 6, lane = threadIdx.x & 63;
    const int half = lane >> 5, hl = lane & 31;
    const int node = blockIdx.x * 8 + wave * 2 + half;
    const bool valid = node < N_NODES;
    const int md = *mode;
    int s = 0, deg = 0;
    if (valid) { s = row_ptr[node]; deg = row_ptr[node + 1] - s; }
    float a0 = 0.f, a1 = 0.f;
    if (md) {
        const float* xf = (const float*)xv;
        if (valid && hl < 24) {
            float2 v = *reinterpret_cast<const float2*>(xf + (size_t)node * C_IN + 2 * hl);
            a0 = v.x; a1 = v.y;
        }
        for (int i = 0; i < deg; i += 2) {
            const int id0 = col_idx[s + i];
            const bool h1 = (i + 1) < deg;
            const int id1 = h1 ? col_idx[s + i + 1] : 0;
            if (hl < 24) {
                float2 w0 = *reinterpret_cast<const float2*>(xf + (size_t)id0 * C_IN + 2 * hl);
                float2 w1 = make_float2(0.f, 0.f);
                if (h1) w1 = *reinterpret_cast<const float2*>(xf + (size_t)id1 * C_IN + 2 * hl);
                a0 += w0.x + w1.x; a1 += w0.y + w1.y;
            }
        }
    } else {
        const u16* xh = (const u16*)xv;
        if (valid && hl < 24) {
            u32 v = *reinterpret_cast<const u32*>(xh + (size_t)node * C_IN + 2 * hl);
            a0 = bf2f_lo(v); a1 = bf2f_hi(v);
        }
        for (int i = 0; i < deg; i += 2) {
            const int id0 = col_idx[s + i];
            const bool h1 = (i + 1) < deg;
            const int id1 = h1 ? col_idx[s + i + 1] : 0;
            if (hl < 24) {
                u32 w0 = *reinterpret_cast<const u32*>(xh + (size_t)id0 * C_IN + 2 * hl);
                u32 w1 = 0;
                if (h1) w1 = *reinterpret_cast<const u32*>(xh + (size_t)id1 * C_IN + 2 * hl);
                a0 += bf2f_lo(w0) + bf2f_lo(w1);
                a1 += bf2f_hi(w0) + bf2f_hi(w1);
            }
        }
    }
    if (valid) {
        const u32 w = (hl < 24) ? pack2(a0, a1) : 0u;
        *reinterpret_cast<u32*>(z + (size_t)node * HD + 2 * hl) = w;           // cols 0..63
        *reinterpret_cast<u32*>(z + (size_t)node * HD + 64 + 2 * hl) = 0u;     // cols 64..127
    }
}

// ---------------- plain MFMA GEMM: BM=64, LDS A-stage, direct-store epilogue ----------------
// TRANS applies lrelu(cA*x+cB) while staging; STATS accumulates column sum/sumsq into
// NREP-replicated stats. IN-PLACE SAFE (out == A): block reads only its own rows.
template <int TRANS, int STATS>
__global__ __launch_bounds__(256) void gemm_mfma(const u16* A, const u16* __restrict__ wp,
                                                 const float* __restrict__ biasf,
                                                 const float* __restrict__ coef,
                                                 u16* out, float* __restrict__ stats) {
    __shared__ u16 Asm[64][136];
    __shared__ float sred[4][128];
    __shared__ float sqred[4][128];
    const int tid = threadIdx.x;
    const int m0 = blockIdx.x * 64;
    const int rrow = tid >> 4;   // 0..15
    const int seg = tid & 15;    // cols seg*8..seg*8+7

    {
        float cA[8], cB[8];
        if (TRANS) {
            #pragma unroll
            for (int j = 0; j < 8; ++j) {
                cA[j] = coef[seg * 8 + j];
                cB[j] = coef[128 + seg * 8 + j];
            }
        }
        uint4 v[4];
        #pragma unroll
        for (int i = 0; i < 4; ++i) {
            const int gm = m0 + i * 16 + rrow;
            if (gm < N_NODES) v[i] = *reinterpret_cast<const uint4*>(A + (size_t)gm * HD + seg * 8);
            else { v[i].x = 0; v[i].y = 0; v[i].z = 0; v[i].w = 0; }
        }
        #pragma unroll
        for (int i = 0; i < 4; ++i) {
            uint4 o = v[i];
            if (TRANS) {
                u32 w[4] = {o.x, o.y, o.z, o.w};
                #pragma unroll
                for (int p = 0; p < 4; ++p) {
                    const float lo = lrelu(cA[2 * p] * bf2f_lo(w[p]) + cB[2 * p]);
                    const float hi = lrelu(cA[2 * p + 1] * bf2f_hi(w[p]) + cB[2 * p + 1]);
                    w[p] = pack2(lo, hi);
                }
                o.x = w[0]; o.y = w[1]; o.z = w[2]; o.w = w[3];
            }
            *reinterpret_cast<uint4*>(&Asm[i * 16 + rrow][seg * 8]) = o;
        }
    }
    __syncthreads();

    const int wave = tid >> 6, lane = tid & 63;
    const int quad = lane >> 4, lx = lane & 15;
    f32x4 acc[8] = {};
    #pragma unroll 2
    for (int kb = 0; kb < 4; ++kb) {
        bf16x8 bfr[8];
        #pragma unroll
        for (int nt = 0; nt < 8; ++nt)
            bfr[nt] = *reinterpret_cast<const bf16x8*>(wp + (((size_t)(kb * 8 + nt) * 64 + lane) << 3));
        const bf16x8 af = *reinterpret_cast<const bf16x8*>(&Asm[wave * 16 + lx][kb * 32 + quad * 8]);
        #pragma unroll
        for (int nt = 0; nt < 8; ++nt)
            acc[nt] = __builtin_amdgcn_mfma_f32_16x16x32_bf16(af, bfr[nt], acc[nt], 0, 0, 0);
    }

    const int mrow0 = m0 + wave * 16;
    #pragma unroll
    for (int nt = 0; nt < 8; ++nt) {
        const int n = nt * 16 + lx;
        const float bj = biasf[n];
        float s = 0.f, q = 0.f;
        #pragma unroll
        for (int r = 0; r < 4; ++r) {
            const int m = mrow0 + quad * 4 + r;
            if (m < N_NODES) {
                const float v = acc[nt][r] + bj;
                out[(size_t)m * HD + n] = f2bf(v);
                if (STATS) { s += v; q += v * v; }
            }
        }
        if (STATS) {
            s += __shfl_xor(s, 16); s += __shfl_xor(s, 32);
            q += __shfl_xor(q, 16); q += __shfl_xor(q, 32);
            if (quad == 0) { sred[wave][n] = s; sqred[wave][n] = q; }
        }
    }
    if (STATS) {
        __syncthreads();
        float* sdst = stats + (size_t)(blockIdx.x & (NREP - 1)) * 256;
        if (tid < 128) {
            atomicAdd(&sdst[tid], sred[0][tid] + sred[1][tid] + sred[2][tid] + sred[3][tid]);
        } else if (tid < 256) {
            const int c2 = tid - 128;
            atomicAdd(&sdst[128 + c2], sqred[0][c2] + sqred[1][c2] + sqred[2][c2] + sqred[3][c2]);
        }
    }
}

// ---------------- FUSED gather+BN+lrelu GEMM (layers 1..5 first MLP linear) ----------------
// Staging computes z-row = f(U[gm]) + sum_{j in N(gm)} f(U[j]) directly into LDS (no z buffer).
// NOT in-place: reads arbitrary U rows -> out must differ from U. STATS always on.
__global__ __launch_bounds__(256) void gemm_gather(const u16* __restrict__ U, const int* __restrict__ row_ptr,
                                                   const int* __restrict__ col_idx, const u16* __restrict__ wp,
                                                   const float* __restrict__ biasf, const float* __restrict__ coef,
                                                   u16* __restrict__ out, float* __restrict__ stats) {
    __shared__ u16 Asm[64][136];
    __shared__ float sred[4][128];
    __shared__ float sqred[4][128];
    const int tid = threadIdx.x;
    const int m0 = blockIdx.x * 64;
    const int rrow = tid >> 4;
    const int seg = tid & 15;

    {
        float cA[8], cB[8];
        #pragma unroll
        for (int j = 0; j < 8; ++j) {
            cA[j] = coef[seg * 8 + j];
            cB[j] = coef[128 + seg * 8 + j];
        }
        for (int i = 0; i < 4; ++i) {
            const int gm = m0 + i * 16 + rrow;
            float a[8];
            #pragma unroll
            for (int j = 0; j < 8; ++j) a[j] = 0.f;
            if (gm < N_NODES) {
                const uint4 v = *reinterpret_cast<const uint4*>(U + (size_t)gm * HD + seg * 8);
                const u32 w[4] = {v.x, v.y, v.z, v.w};
                #pragma unroll
                for (int p = 0; p < 4; ++p) {
                    a[2 * p]     = lrelu(cA[2 * p] * bf2f_lo(w[p]) + cB[2 * p]);
                    a[2 * p + 1] = lrelu(cA[2 * p + 1] * bf2f_hi(w[p]) + cB[2 * p + 1]);
                }
                const int s = row_ptr[gm];
                const int deg = row_ptr[gm + 1] - s;
                for (int t = 0; t < deg; t += 2) {
                    const int id0 = col_idx[s + t];
                    const bool h1 = (t + 1) < deg;
                    const int id1 = h1 ? col_idx[s + t + 1] : 0;
                    const uint4 r0 = *reinterpret_cast<const uint4*>(U + (size_t)id0 * HD + seg * 8);
                    uint4 r1; r1.x = r1.y = r1.z = r1.w = 0;
                    if (h1) r1 = *reinterpret_cast<const uint4*>(U + (size_t)id1 * HD + seg * 8);
                    const u32 w0[4] = {r0.x, r0.y, r0.z, r0.w};
                    const u32 w1[4] = {r1.x, r1.y, r1.z, r1.w};
                    #pragma unroll
                    for (int p = 0; p < 4; ++p) {
                        a[2 * p]     += lrelu(cA[2 * p] * bf2f_lo(w0[p]) + cB[2 * p]);
                        a[2 * p + 1] += lrelu(cA[2 * p + 1] * bf2f_hi(w0[p]) + cB[2 * p + 1]);
                        if (h1) {
                            a[2 * p]     += lrelu(cA[2 * p] * bf2f_lo(w1[p]) + cB[2 * p]);
                            a[2 * p + 1] += lrelu(cA[2 * p + 1] * bf2f_hi(w1[p]) + cB[2 * p + 1]);
                        }
                    }
                }
            }
            uint4 o;
            o.x = pack2(a[0], a[1]); o.y = pack2(a[2], a[3]);
            o.z = pack2(a[4], a[5]); o.w = pack2(a[6], a[7]);
            *reinterpret_cast<uint4*>(&Asm[i * 16 + rrow][seg * 8]) = o;
        }
    }
    __syncthreads();

    const int wave = tid >> 6, lane = tid & 63;
    const int quad = lane >> 4, lx = lane & 15;
    f32x4 acc[8] = {};
    #pragma unroll 2
    for (int kb = 0; kb < 4; ++kb) {
        bf16x8 bfr[8];
        #pragma unroll
        for (int nt = 0; nt < 8; ++nt)
            bfr[nt] = *reinterpret_cast<const bf16x8*>(wp + (((size_t)(kb * 8 + nt) * 64 + lane) << 3));
        const bf16x8 af = *reinterpret_cast<const bf16x8*>(&Asm[wave * 16 + lx][kb * 32 + quad * 8]);
        #pragma unroll
        for (int nt = 0; nt < 8; ++nt)
            acc[nt] = __builtin_amdgcn_mfma_f32_16x16x32_bf16(af, bfr[nt], acc[nt], 0, 0, 0);
    }

    const int mrow0 = m0 + wave * 16;
    #pragma unroll
    for (int nt = 0; nt < 8; ++nt) {
        const int n = nt * 16 + lx;
        const float bj = biasf[n];
        float s = 0.f, q = 0.f;
        #pragma unroll
        for (int r = 0; r < 4; ++r) {
            const int m = mrow0 + quad * 4 + r;
            if (m < N_NODES) {
                const float v = acc[nt][r] + bj;
                out[(size_t)m * HD + n] = f2bf(v);
                s += v; q += v * v;
            }
        }
        s += __shfl_xor(s, 16); s += __shfl_xor(s, 32);
        q += __shfl_xor(q, 16); q += __shfl_xor(q, 32);
        if (quad == 0) { sred[wave][n] = s; sqred[wave][n] = q; }
    }
    __syncthreads();
    float* sdst = stats + (size_t)(blockIdx.x & (NREP - 1)) * 256;
    if (tid < 128) {
        atomicAdd(&sdst[tid], sred[0][tid] + sred[1][tid] + sred[2][tid] + sred[3][tid]);
    } else if (tid < 256) {
        const int c2 = tid - 128;
        atomicAdd(&sdst[128 + c2], sqred[0][c2] + sqred[1][c2] + sqred[2][c2] + sqred[3][c2]);
    }
}

// ---------------- pooling: wave per graph, uint4 row loads, quad-parallel rows ----------------
__global__ __launch_bounds__(256) void pool_kernel(const u16* __restrict__ hf, const int* __restrict__ batch,
                                                   const int* __restrict__ mode, float* __restrict__ emb,
                                                   void* __restrict__ outv) {
    const int wave = threadIdx.x >> 6, lane = threadIdx.x & 63;
    const int g = blockIdx.x * 4 + wave;
    if (g >= N_GRAPHS) return;
    const int md = *mode;
    const int quad = lane >> 4, c = lane & 15;
    int lo = 0, hi = N_NODES;
    while (lo < hi) { int m = (lo + hi) >> 1; if (batch[m] < g) lo = m + 1; else hi = m; }
    const int s = lo;
    hi = N_NODES;
    while (lo < hi) { int m = (lo + hi) >> 1; if (batch[m] < g + 1) lo = m + 1; else hi = m; }
    const int e = lo;
    const int cnt = e - s;
    float sum[8], mx[8];
    #pragma unroll
    for (int j = 0; j < 8; ++j) { sum[j] = 0.f; mx[j] = -INFINITY; }
    for (int n = s + quad; n < e; n += 4) {
        const uint4 v = *reinterpret_cast<const uint4*>(hf + (size_t)n * HD + c * 8);
        const u32 w[4] = {v.x, v.y, v.z, v.w};
        #pragma unroll
        for (int p = 0; p < 4; ++p) {
            const float f0 = bf2f_lo(w[p]), f1 = bf2f_hi(w[p]);
            sum[2 * p] += f0; sum[2 * p + 1] += f1;
            mx[2 * p] = fmaxf(mx[2 * p], f0); mx[2 * p + 1] = fmaxf(mx[2 * p + 1], f1);
        }
    }
    #pragma unroll
    for (int j = 0; j < 8; ++j) {
        sum[j] += __shfl_xor(sum[j], 16); sum[j] += __shfl_xor(sum[j], 32);
        mx[j] = fmaxf(mx[j], __shfl_xor(mx[j], 16));
        mx[j] = fmaxf(mx[j], __shfl_xor(mx[j], 32));
    }
    if (quad == 0) {
        const float invc = 1.0f / (float)max(cnt, 1);
        const size_t base = (size_t)N_GRAPHS * 3 + (size_t)g * 256;
        #pragma unroll
        for (int j = 0; j < 8; ++j) {
            const float mean = sum[j] * invc;
            const float m2 = (cnt == 0) ? 0.f : mx[j];
            const int col = c * 8 + j;
            emb[(size_t)g * 256 + col] = mean;
            emb[(size_t)g * 256 + 128 + col] = m2;
            if (md) {
                ((float*)outv)[base + col] = mean;
                ((float*)outv)[base + 128 + col] = m2;
            } else {
                ((u16*)outv)[base + col] = f2bf(mean);
                ((u16*)outv)[base + 128 + col] = f2bf(m2);
            }
        }
    }
}

__global__ __launch_bounds__(64) void final_kernel(const float* __restrict__ emb, const void* __restrict__ fcwv,
                                                   const void* __restrict__ fcbv, const void* __restrict__ fc2wv,
                                                   const void* __restrict__ fc2bv, const int* __restrict__ mode,
                                                   void* __restrict__ outv) {
    __shared__ float es[256];
    __shared__ float hs[64];
    const int g = blockIdx.x, t = threadIdx.x;
    const int md = *mode;
    reinterpret_cast<float4*>(es)[t] = reinterpret_cast<const float4*>(emb + (size_t)g * 256)[t];
    __syncthreads();
    float acc = md ? ((const float*)fcbv)[t] : bf2f(((const u16*)fcbv)[t]);
    if (md) {
        const float* w = (const float*)fcwv;
        #pragma unroll 8
        for (int k = 0; k < 256; ++k) acc += es[k] * w[k * 64 + t];
    } else {
        const u16* w = (const u16*)fcwv;
        #pragma unroll 8
        for (int k = 0; k < 256; ++k) acc += es[k] * bf2f(w[k * 64 + t]);
    }
    hs[t] = lrelu(acc);
    __syncthreads();
    if (t < 3) {
        float o = md ? ((const float*)fc2bv)[t] : bf2f(((const u16*)fc2bv)[t]);
        if (md) {
            const float* w = (const float*)fc2wv;
            #pragma unroll 8
            for (int j = 0; j < 64; ++j) o += hs[j] * w[j * 3 + t];
            ((float*)outv)[(size_t)g * 3 + t] = o;
        } else {
            const u16* w = (const u16*)fc2wv;
            #pragma unroll 8
            for (int j = 0; j < 64; ++j) o += hs[j] * bf2f(w[j * 3 + t]);
            ((u16*)outv)[(size_t)g * 3 + t] = f2bf(o);
        }
    }
}

// ---------------- launch ----------------
static inline size_t align256(size_t x) { return (x + 255) & ~(size_t)255; }

extern "C" void kernel_launch(void* const* d_in, const int* in_sizes, int n_in,
                              void* d_out, int out_size, void* d_ws, size_t ws_size,
                              hipStream_t stream) {
    (void)in_sizes; (void)n_in; (void)out_size; (void)ws_size;
    const void* x    = d_in[0];
    const void* W1a  = d_in[2];
    const void* W1b  = d_in[3];
    const void* b1   = d_in[4];
    const void* g1   = d_in[5];
    const void* be1  = d_in[6];
    const void* W2   = d_in[7];
    const void* b2   = d_in[8];
    const void* gn   = d_in[9];
    const void* bnb  = d_in[10];
    const void* fcw  = d_in[11];
    const void* fcb  = d_in[12];
    const void* fc2w = d_in[13];
    const void* fc2b = d_in[14];
    const int* ei    = (const int*)d_in[15];
    const int* batch = (const int*)d_in[16];

    char* p = (char*)d_ws;
    size_t off = 0;
    u16* zb = (u16*)(p + off); off += align256((size_t)N_NODES * HD * 2);
    u16* hb = (u16*)(p + off); off += align256((size_t)N_NODES * HD * 2);
    u16* wpack = (u16*)(p + off); off += align256((size_t)12 * HD * HD * 2);
    float* biasf = (float*)(p + off); off += align256((size_t)12 * HD * 4);
    float* emb = (float*)(p + off); off += align256((size_t)N_GRAPHS * 256 * 4);
    int* row_ptr = (int*)(p + off); off += align256((size_t)(N_NODES + 1) * 4);
    int* cursor = (int*)(p + off); off += align256((size_t)N_NODES * 4);
    int* col_idx = (int*)(p + off); off += align256((size_t)N_EDGES * 4);
    int* bsum = (int*)(p + off); off += align256((size_t)SB * 4);
    // 12 per-layer stats slots, zeroed once: slot l (0..5) = gemm1 stats of layer l;
    // slot 6+l (0..4) = gemm2 stats of layer l.
    float* statsAll = (float*)(p + off); off += align256((size_t)12 * NREP * 256 * 4);
    float* coefA = (float*)(p + off); off += align256(256 * 4);
    float* coefB = (float*)(p + off); off += align256(256 * 4);
    int* mode = (int*)(p + off); off += align256(4);

    const int EB = (N_EDGES + 255) / 256;
    const int AG0 = (N_NODES + 7) / 8;       // 12500 (2 nodes/wave)
    const int GBM = (N_NODES + 63) / 64;     // 1563

    detect_kernel<<<1, 256, 0, stream>>>((const u16*)x, mode);

    hipMemsetAsync(cursor, 0, (size_t)N_NODES * 4, stream);
    hipMemsetAsync(statsAll, 0, (size_t)12 * NREP * 256 * 4, stream);
    hist_kernel<<<EB, 256, 0, stream>>>(ei + N_EDGES, cursor);
    scan1_kernel<<<SB, 256, 0, stream>>>(cursor, bsum);
    scan2_kernel<<<1, 512, 0, stream>>>(bsum, row_ptr);
    scan3_kernel<<<SB, 256, 0, stream>>>(cursor, bsum, row_ptr);
    hipMemcpyAsync(cursor, row_ptr, (size_t)N_NODES * 4, hipMemcpyDeviceToDevice, stream);
    fill_kernel<<<EB, 256, 0, stream>>>(ei, ei + N_EDGES, cursor, col_idx);
    pack_w_kernel<<<96, 256, 0, stream>>>(W1a, W1b, W2, mode, wpack);
    pack_b_kernel<<<6, 256, 0, stream>>>(b1, b2, mode, biasf);

    u16* cur = zb;
    u16* oth = hb;
    for (int l = 0; l < NLAYERS; ++l) {
        float* statsA = statsAll + (size_t)l * NREP * 256;
        float* statsB = statsAll + (size_t)(6 + l) * NREP * 256;
        if (l == 0) {
            agg0_kernel<<<AG0, 256, 0, stream>>>(x, row_ptr, col_idx, mode, cur);
            gemm_mfma<0, 1><<<GBM, 256, 0, stream>>>(cur, wpack + (size_t)l * HD * HD,
                                                     biasf + (size_t)l * HD, nullptr, cur, statsA);
        } else {
            // fused gather+BN+lrelu + gemm1: cur -> oth (not in-place)
            gemm_gather<<<GBM, 256, 0, stream>>>(cur, row_ptr, col_idx,
                                                 wpack + (size_t)l * HD * HD,
                                                 biasf + (size_t)l * HD, coefB, oth, statsA);
            u16* t = cur; cur = oth; oth = t;
        }
        finalize_kernel<<<1, 128, 0, stream>>>(statsA, g1, be1, (size_t)l * HD, mode, coefA);
        if (l < NLAYERS - 1) {
            gemm_mfma<1, 1><<<GBM, 256, 0, stream>>>(cur, wpack + (size_t)(6 + l) * HD * HD,
                                                     biasf + (size_t)(6 + l) * HD, coefA, cur, statsB);
            finalize_kernel<<<1, 128, 0, stream>>>(statsB, gn, bnb, (size_t)l * HD, mode, coefB);
        } else {
            gemm_mfma<1, 0><<<GBM, 256, 0, stream>>>(cur, wpack + (size_t)(6 + l) * HD * HD,
                                                     biasf + (size_t)(6 + l) * HD, coefA, cur, nullptr);
        }
    }

    pool_kernel<<<(N_GRAPHS + 3) / 4, 256, 0, stream>>>(cur, batch, mode, emb, d_out);
    final_kernel<<<N_GRAPHS, 64, 0, stream>>>(emb, fcw, fcb, fc2w, fc2b, mode, d_out);
}